// Round 9
// baseline (176.170 us; speedup 1.0000x reference)
//
#include <hip/hip_runtime.h>
#include <hip/hip_bf16.h>

#define B_ 8
#define N_ 2048
#define D_ 32
#define RCAP 16                        // CSR entries per row (P(row>16) ~ 1e-15)
#define EM1_DIAG 1.7182818284590452f   // e^1 - 1
#define M_   8.0f
#define EM_  2980.9579870417283f       // e^8
#define L2E  1.4426950408889634f
#define LN2  0.6931471805599453f
#define MH_  (0.5f * M_ * L2E)         // 0.5*M in base-2 units

typedef __attribute__((ext_vector_type(8))) short short8;
typedef __attribute__((ext_vector_type(4))) float f32x4;

// ---------------------------------------------------------------------------
// Setup: bf16 copies of x,y, half-norms ||r||^2/2, zero the CSR counters.
// ---------------------------------------------------------------------------
__global__ void setup_kernel(const float* __restrict__ x, const float* __restrict__ y,
                             unsigned short* __restrict__ xb, unsigned short* __restrict__ yb,
                             float* __restrict__ NX, float* __restrict__ NY,
                             int* __restrict__ csr_cnt)
{
    int t = blockIdx.x * 256 + threadIdx.x;          // 0..32767
    const float* src = (t < 16384) ? x : y;
    unsigned short* dstb = (t < 16384) ? xb : yb;
    float* dstn = (t < 16384) ? NX : NY;
    int row = (t < 16384) ? t : (t - 16384);
    const float4* p = reinterpret_cast<const float4*>(src + (size_t)row * D_);
    float ss = 0.f;
    float4 v[8];
    #pragma unroll
    for (int k = 0; k < 8; k++) {
        v[k] = p[k];
        ss += v[k].x * v[k].x + v[k].y * v[k].y + v[k].z * v[k].z + v[k].w * v[k].w;
    }
    short8* dst8 = reinterpret_cast<short8*>(dstb + (size_t)row * D_);
    #pragma unroll
    for (int k = 0; k < 4; k++) {
        const float fv[8] = { v[2*k].x, v[2*k].y, v[2*k].z, v[2*k].w,
                              v[2*k+1].x, v[2*k+1].y, v[2*k+1].z, v[2*k+1].w };
        short8 o;
        #pragma unroll
        for (int e = 0; e < 8; e++) {
            __hip_bfloat16 h = __float2bfloat16(fv[e]);
            o[e] = *reinterpret_cast<const short*>(&h);
        }
        dst8[k] = o;
    }
    dstn[row] = ss * 0.5f;
    csr_cnt[2 * t] = 0;                              // 4*8*2048 = 65536 counters
    csr_cnt[2 * t + 1] = 0;
}

// ---------------------------------------------------------------------------
// Pair discovery. Grid = 3 x 8 x 32 rowblocks x 4 colchunks = 3072 blocks
// (12/CU) + store/atomic-free phase-1 mask scan (loads pipeline freely).
// Phase 2 re-walks the ~1 surviving step per wave and emits row-CSR entries
// (col, e^G - 1) into tables 0=xx, 1=yy, 2=yx, 3=xy(=yx^T).
// ---------------------------------------------------------------------------
__global__ __launch_bounds__(256) void discover_kernel(
    const unsigned short* __restrict__ xb, const unsigned short* __restrict__ yb,
    const float* __restrict__ NX, const float* __restrict__ NY,
    int* __restrict__ csr_cnt, uint2* __restrict__ csr_ent)
{
    int m = blockIdx.x >> 10;                         // matrix 0=xx 1=yy 2=yx
    int rem = blockIdx.x & 1023;
    int batch = rem >> 7;                             // 8 batches
    int rem2 = rem & 127;
    int rowblk = rem2 >> 2;                           // 32 blocks of 64 rows
    int cchunk = rem2 & 3;                            // 4 chunks of 512 cols
    const unsigned short* rd = (m == 0) ? xb : yb;
    const float*          rN = (m == 0) ? NX : NY;
    const unsigned short* cd = (m == 1) ? yb : xb;
    const float*          cN = (m == 1) ? NY : NX;

    const int tid = threadIdx.x, lane = tid & 63, wv = tid >> 6;
    const int r0 = rowblk * 64;
    const size_t rowbase = (size_t)batch * N_ + r0;

    short8 afrag[4];
    f32x4 cinit[4];
    #pragma unroll
    for (int g = 0; g < 4; g++) {
        afrag[g] = *reinterpret_cast<const short8*>(
            rd + (rowbase + g * 16 + (lane & 15)) * D_ + (lane >> 4) * 8);
        float4 nv = *reinterpret_cast<const float4*>(
            rN + rowbase + g * 16 + (lane >> 4) * 4);
        cinit[g][0] = -nv.x; cinit[g][1] = -nv.y; cinit[g][2] = -nv.z; cinit[g][3] = -nv.w;
    }
    const unsigned short* cdB = cd + (size_t)batch * N_ * D_;
    const float* cNB = cN + batch * N_;
    const int c0w = cchunk * 512 + wv * 128;

    // ---- phase 1: branch-free survivor scan (8 iters, fully unrolled) -----
    unsigned mask = 0;
    #pragma unroll
    for (int cc = 0; cc < 8; ++cc) {
        int col = c0w + cc * 16 + (lane & 15);
        short8 bfrag = *reinterpret_cast<const short8*>(
            cdB + (size_t)col * D_ + (lane >> 4) * 8);
        float ny = cNB[col];
        f32x4 d[4];
        #pragma unroll
        for (int g = 0; g < 4; g++)
            d[g] = __builtin_amdgcn_mfma_f32_16x16x32_bf16(afrag[g], bfrag, cinit[g], 0, 0, 0);
        float m0 = fmaxf(fmaxf(d[0][0], d[0][1]), fmaxf(d[0][2], d[0][3]));
        float m1 = fmaxf(fmaxf(d[1][0], d[1][1]), fmaxf(d[1][2], d[1][3]));
        float m2 = fmaxf(fmaxf(d[2][0], d[2][1]), fmaxf(d[2][2], d[2][3]));
        float m3 = fmaxf(fmaxf(d[3][0], d[3][1]), fmaxf(d[3][2], d[3][3]));
        float mx = fmaxf(fmaxf(m0, m1), fmaxf(m2, m3));
        mask |= (__any(mx > ny - 10.0f) ? 1u : 0u) << cc;
    }

    // ---- phase 2: emit (rare) ---------------------------------------------
    auto push = [&](int T, int row, int colv, float em1) {
        size_t base = (size_t)(T * B_ + batch) * N_ + row;
        int idx = atomicAdd(&csr_cnt[base], 1);
        if (idx < RCAP)
            csr_ent[base * RCAP + idx] = make_uint2((unsigned)colv, __float_as_uint(em1));
    };
    while (mask) {
        int cc = __builtin_ctz(mask);
        mask &= mask - 1;
        int col = c0w + cc * 16 + (lane & 15);
        short8 bfrag = *reinterpret_cast<const short8*>(
            cdB + (size_t)col * D_ + (lane >> 4) * 8);
        float ny = cNB[col];
        f32x4 d[4];
        #pragma unroll
        for (int g = 0; g < 4; g++)
            d[g] = __builtin_amdgcn_mfma_f32_16x16x32_bf16(afrag[g], bfrag, cinit[g], 0, 0, 0);
        #pragma unroll
        for (int g = 0; g < 4; g++) {
            #pragma unroll
            for (int r = 0; r < 4; r++) {
                float dist = ny - d[g][r];
                if (dist < 10.0f) {
                    int i = r0 + g * 16 + (lane >> 4) * 4 + r;
                    if (m == 2) {
                        float em1 = __expf(__expf(-fmaxf(dist, 0.f))) - 1.0f;
                        push(2, i, col, em1);
                        push(3, col, i, em1);
                    } else if (i != col) {
                        float em1 = __expf(__expf(-fmaxf(dist, 0.f))) - 1.0f;
                        push(m, i, col, em1);
                    }
                }
            }
        }
    }
}

// ---------------------------------------------------------------------------
// Whole Sinkhorn loop, one 1024-thread block per batch. Gather formulation,
// ONE barrier per stage (21 total). Potentials/weights in registers (base-2):
//   ev = exp2(W + F);  F' = 0.5F - (0.5*log2(tot) + MH_)
// CSR entries: first 2 per (table,row) REGISTER-CACHED at entry (global
// fallback only for cnt>2) — removes global latency from the per-stage chain.
// S-reduction: per-wave shfl partial -> unique slot Spart[par][tbl][wv]
// (no atomics, no zeroing) -> post-barrier tree16 by every thread.
// evb/Spart parity double-buffered; reuse 2 stages apart fenced by barriers.
// ---------------------------------------------------------------------------
__global__ __launch_bounds__(1024) void sinkhorn_kernel(
    const float* __restrict__ a_in, const float* __restrict__ b_in,
    const int* __restrict__ csr_cnt, const uint2* __restrict__ csr_ent,
    float* __restrict__ out)
{
    __shared__ float evb[2][4][N_];     // 64 KB  [parity][slot][col]
    __shared__ float Spart[2][4][16];   // [parity][table][wave]
    __shared__ float resacc;

    const int batch = blockIdx.x;
    const int t = threadIdx.x, lane = t & 63, wv = t >> 6;

    int cnts[4][2];
    const uint2* ebase[4];
    uint2 ec[4][2][2];                  // cached entries [table][q][k]
    #pragma unroll
    for (int T = 0; T < 4; T++) {
        size_t bb = (size_t)(T * B_ + batch) * N_;
        ebase[T] = csr_ent + bb * (size_t)RCAP;
        #pragma unroll
        for (int q = 0; q < 2; q++) {
            int row = t + 1024 * q;
            int c = min(csr_cnt[bb + row], RCAP);
            cnts[T][q] = c;
            const uint2* E = ebase[T] + (size_t)row * RCAP;
            ec[T][q][0] = (c > 0) ? E[0] : make_uint2(0u, 0u);
            ec[T][q][1] = (c > 1) ? E[1] : make_uint2(0u, 0u);
        }
    }
    float AW[2], BW[2];
    float F0[2] = {0.f, 0.f}, F1[2] = {0.f, 0.f}, F2[2] = {0.f, 0.f}, F3[2] = {0.f, 0.f};
    #pragma unroll
    for (int q = 0; q < 2; q++) {
        int j = t + 1024 * q;
        AW[q] = (a_in[batch * N_ + j] - M_) * L2E;
        BW[q] = (b_in[batch * N_ + j] - M_) * L2E;
    }
    if (t == 0) resacc = 0.f;
    __syncthreads();

    // gather over this thread's CSR row: cached entries + rare global tail
    auto gath = [&](int T, int q, const float* evbuf) -> float {
        int c = cnts[T][q];
        float g = 0.f;
        if (c > 0) g += evbuf[ec[T][q][0].x] * __uint_as_float(ec[T][q][0].y);
        if (c > 1) g += evbuf[ec[T][q][1].x] * __uint_as_float(ec[T][q][1].y);
        if (__builtin_expect(c > 2, 0)) {
            const uint2* E = ebase[T] + (size_t)(t + 1024 * q) * RCAP;
            for (int k = 2; k < c; ++k)
                g += evbuf[E[k].x] * __uint_as_float(E[k].y);
        }
        return g;
    };
    auto wpart = [&](float v, float* slot) {
        #pragma unroll
        for (int off = 1; off < 64; off <<= 1) v += __shfl_xor(v, off, 64);
        if (lane == 0) *slot = v;
    };
    auto tree16 = [](const float* r) -> float {
        return (((r[0] + r[1]) + (r[2] + r[3])) + ((r[4] + r[5]) + (r[6] + r[7])))
             + (((r[8] + r[9]) + (r[10] + r[11])) + ((r[12] + r[13]) + (r[14] + r[15])));
    };

    // stage A: fxx (T0, slot0, diag), fyx (T2, slot1), fyy (T1, slot2, diag)
    auto stageA = [&](int s) {
        const int p = s & 1;
        float e0q[2], e2q[2];
        float s0 = 0.f, s1 = 0.f, s2 = 0.f;
        #pragma unroll
        for (int q = 0; q < 2; q++) {
            int j = t + 1024 * q;
            float e0 = __builtin_amdgcn_exp2f(AW[q] + F0[q]); evb[p][0][j] = e0; e0q[q] = e0; s0 += e0;
            float e1 = __builtin_amdgcn_exp2f(AW[q] + F2[q]); evb[p][1][j] = e1;              s1 += e1;
            float e2 = __builtin_amdgcn_exp2f(BW[q] + F3[q]); evb[p][2][j] = e2; e2q[q] = e2; s2 += e2;
        }
        wpart(s0, &Spart[p][0][wv]);
        wpart(s1, &Spart[p][1][wv]);
        wpart(s2, &Spart[p][2][wv]);
        __syncthreads();
        float S0 = tree16(Spart[p][0]);
        float S1 = tree16(Spart[p][1]);
        float S2 = tree16(Spart[p][2]);
        #pragma unroll
        for (int q = 0; q < 2; q++) {
            float g0 = gath(0, q, evb[p][0]);
            float g1 = gath(2, q, evb[p][1]);
            float g2 = gath(1, q, evb[p][2]);
            float lg0 = __builtin_amdgcn_logf(S0 + fmaf(e0q[q], EM1_DIAG, g0));
            float lg1 = __builtin_amdgcn_logf(S1 + g1);
            float lg2 = __builtin_amdgcn_logf(S2 + fmaf(e2q[q], EM1_DIAG, g2));
            F0[q] = fmaf(0.5f, F0[q], -fmaf(0.5f, lg0, MH_));
            F1[q] = fmaf(0.5f, F1[q], -fmaf(0.5f, lg1, MH_));
            F3[q] = fmaf(0.5f, F3[q], -fmaf(0.5f, lg2, MH_));
        }
    };

    // stage B: fxy (T3, cols y, c = b + fyx_new)
    auto stageB = [&](int s) {
        const int p = s & 1;
        float sB = 0.f;
        #pragma unroll
        for (int q = 0; q < 2; q++) {
            int j = t + 1024 * q;
            float e = __builtin_amdgcn_exp2f(BW[q] + F1[q]); evb[p][0][j] = e; sB += e;
        }
        wpart(sB, &Spart[p][0][wv]);
        __syncthreads();
        float S = tree16(Spart[p][0]);
        #pragma unroll
        for (int q = 0; q < 2; q++) {
            float g = gath(3, q, evb[p][0]);
            F2[q] = fmaf(0.5f, F2[q], -fmaf(0.5f, __builtin_amdgcn_logf(S + g), MH_));
        }
    };

    int s = 0;
    for (int it = 0; it < 10; ++it) {
        stageA(s); ++s;
        stageB(s); ++s;
    }

    // stage E (s=20): 4 extrapolation LSEs + fused weighted reduce.
    // r = M + LN2*lg; in (r0-r2), (r3-r1) the M cancels.
    {
        const int p = s & 1;
        float e0q[2], e3q[2];
        float s0 = 0.f, s1 = 0.f, s2 = 0.f, s3 = 0.f;
        #pragma unroll
        for (int q = 0; q < 2; q++) {
            int j = t + 1024 * q;
            float e0 = __builtin_amdgcn_exp2f(AW[q] + F0[q]); evb[p][0][j] = e0; e0q[q] = e0; s0 += e0; // xx
            float e1 = __builtin_amdgcn_exp2f(AW[q] + F2[q]); evb[p][1][j] = e1;              s1 += e1; // yx
            float e2 = __builtin_amdgcn_exp2f(BW[q] + F1[q]); evb[p][2][j] = e2;              s2 += e2; // xy
            float e3 = __builtin_amdgcn_exp2f(BW[q] + F3[q]); evb[p][3][j] = e3; e3q[q] = e3; s3 += e3; // yy
        }
        wpart(s0, &Spart[p][0][wv]);
        wpart(s1, &Spart[p][1][wv]);
        wpart(s2, &Spart[p][2][wv]);
        wpart(s3, &Spart[p][3][wv]);
        __syncthreads();
        float S0 = tree16(Spart[p][0]), S1 = tree16(Spart[p][1]);
        float S2 = tree16(Spart[p][2]), S3 = tree16(Spart[p][3]);
        float ctr = 0.f;
        #pragma unroll
        for (int q = 0; q < 2; q++) {
            float lg0 = __builtin_amdgcn_logf(S0 + fmaf(e0q[q], EM1_DIAG, gath(0, q, evb[p][0])));
            float lg1 = __builtin_amdgcn_logf(S1 + gath(2, q, evb[p][1]));
            float lg2 = __builtin_amdgcn_logf(S2 + gath(3, q, evb[p][2]));
            float lg3 = __builtin_amdgcn_logf(S3 + fmaf(e3q[q], EM1_DIAG, gath(1, q, evb[p][3])));
            float ea = __builtin_amdgcn_exp2f(AW[q]);   // e^{a-M}
            float eb = __builtin_amdgcn_exp2f(BW[q]);   // e^{b-M}
            ctr += (lg0 - lg2) * ea + (lg3 - lg1) * eb;
        }
        ctr *= (LN2 * EM_);
        #pragma unroll
        for (int off = 1; off < 64; off <<= 1) ctr += __shfl_xor(ctr, off, 64);
        if (lane == 0) atomicAdd(&resacc, ctr);
        __syncthreads();
        if (t == 0) out[batch] = resacc;   // EPSILON = 1
    }
}

// ---------------------------------------------------------------------------
extern "C" void kernel_launch(void* const* d_in, const int* in_sizes, int n_in,
                              void* d_out, int out_size, void* d_ws, size_t ws_size,
                              hipStream_t stream)
{
    const float* x = (const float*)d_in[0];
    const float* a = (const float*)d_in[1];
    const float* y = (const float*)d_in[2];
    const float* b = (const float*)d_in[3];
    float* out = (float*)d_out;

    char* ws = (char*)d_ws;
    size_t o = 0;
    unsigned short* xb = (unsigned short*)(ws + o); o += (size_t)B_ * N_ * D_ * 2;
    unsigned short* yb = (unsigned short*)(ws + o); o += (size_t)B_ * N_ * D_ * 2;
    float* NX = (float*)(ws + o); o += (size_t)B_ * N_ * 4;
    float* NY = (float*)(ws + o); o += (size_t)B_ * N_ * 4;
    int* csr_cnt = (int*)(ws + o); o += (size_t)4 * B_ * N_ * 4;            // 256 KB
    uint2* csr_ent = (uint2*)(ws + o); o += (size_t)4 * B_ * N_ * RCAP * 8; // 8 MB

    setup_kernel<<<128, 256, 0, stream>>>(x, y, xb, yb, NX, NY, csr_cnt);
    discover_kernel<<<3 * 1024, 256, 0, stream>>>(xb, yb, NX, NY, csr_cnt, csr_ent);
    sinkhorn_kernel<<<B_, 1024, 0, stream>>>(a, b, csr_cnt, csr_ent, out);
}

// Round 10
// 172.514 us; speedup vs baseline: 1.0212x; 1.0212x over previous
//
#include <hip/hip_runtime.h>
#include <hip/hip_bf16.h>

#define B_ 8
#define N_ 2048
#define D_ 32
#define RCAP 16                        // CSR entries per row (P(row>16) ~ 1e-15)
#define EM1_DIAG 1.7182818284590452f   // e^1 - 1
#define M_   8.0f
#define EM_  2980.9579870417283f       // e^8
#define L2E  1.4426950408889634f
#define LN2  0.6931471805599453f
#define MH_  (0.5f * M_ * L2E)         // 0.5*M in base-2 units

typedef __attribute__((ext_vector_type(8))) short short8;
typedef __attribute__((ext_vector_type(4))) float f32x4;

// ---------------------------------------------------------------------------
// Setup: bf16 copies of x,y, half-norms ||r||^2/2, zero the CSR counters.
// ---------------------------------------------------------------------------
__global__ void setup_kernel(const float* __restrict__ x, const float* __restrict__ y,
                             unsigned short* __restrict__ xb, unsigned short* __restrict__ yb,
                             float* __restrict__ NX, float* __restrict__ NY,
                             int* __restrict__ csr_cnt)
{
    int t = blockIdx.x * 256 + threadIdx.x;          // 0..32767
    const float* src = (t < 16384) ? x : y;
    unsigned short* dstb = (t < 16384) ? xb : yb;
    float* dstn = (t < 16384) ? NX : NY;
    int row = (t < 16384) ? t : (t - 16384);
    const float4* p = reinterpret_cast<const float4*>(src + (size_t)row * D_);
    float ss = 0.f;
    float4 v[8];
    #pragma unroll
    for (int k = 0; k < 8; k++) {
        v[k] = p[k];
        ss += v[k].x * v[k].x + v[k].y * v[k].y + v[k].z * v[k].z + v[k].w * v[k].w;
    }
    short8* dst8 = reinterpret_cast<short8*>(dstb + (size_t)row * D_);
    #pragma unroll
    for (int k = 0; k < 4; k++) {
        const float fv[8] = { v[2*k].x, v[2*k].y, v[2*k].z, v[2*k].w,
                              v[2*k+1].x, v[2*k+1].y, v[2*k+1].z, v[2*k+1].w };
        short8 o;
        #pragma unroll
        for (int e = 0; e < 8; e++) {
            __hip_bfloat16 h = __float2bfloat16(fv[e]);
            o[e] = *reinterpret_cast<const short*>(&h);
        }
        dst8[k] = o;
    }
    dstn[row] = ss * 0.5f;
    csr_cnt[2 * t] = 0;                              // 4*8*2048 = 65536 counters
    csr_cnt[2 * t + 1] = 0;
}

// ---------------------------------------------------------------------------
// Pair discovery. Grid = 3 x 8 x 32 rowblocks x 4 colchunks = 3072 blocks,
// store/atomic-free phase-1 mask scan (loads pipeline freely). Phase 2
// re-walks surviving steps and emits row-CSR entries (col, e^G - 1) into
// tables 0=xx, 1=yy, 2=yx, 3=xy(=yx^T).
// ---------------------------------------------------------------------------
__global__ __launch_bounds__(256) void discover_kernel(
    const unsigned short* __restrict__ xb, const unsigned short* __restrict__ yb,
    const float* __restrict__ NX, const float* __restrict__ NY,
    int* __restrict__ csr_cnt, uint2* __restrict__ csr_ent)
{
    int m = blockIdx.x >> 10;                         // matrix 0=xx 1=yy 2=yx
    int rem = blockIdx.x & 1023;
    int batch = rem >> 7;                             // 8 batches
    int rem2 = rem & 127;
    int rowblk = rem2 >> 2;                           // 32 blocks of 64 rows
    int cchunk = rem2 & 3;                            // 4 chunks of 512 cols
    const unsigned short* rd = (m == 0) ? xb : yb;
    const float*          rN = (m == 0) ? NX : NY;
    const unsigned short* cd = (m == 1) ? yb : xb;
    const float*          cN = (m == 1) ? NY : NX;

    const int tid = threadIdx.x, lane = tid & 63, wv = tid >> 6;
    const int r0 = rowblk * 64;
    const size_t rowbase = (size_t)batch * N_ + r0;

    short8 afrag[4];
    f32x4 cinit[4];
    #pragma unroll
    for (int g = 0; g < 4; g++) {
        afrag[g] = *reinterpret_cast<const short8*>(
            rd + (rowbase + g * 16 + (lane & 15)) * D_ + (lane >> 4) * 8);
        float4 nv = *reinterpret_cast<const float4*>(
            rN + rowbase + g * 16 + (lane >> 4) * 4);
        cinit[g][0] = -nv.x; cinit[g][1] = -nv.y; cinit[g][2] = -nv.z; cinit[g][3] = -nv.w;
    }
    const unsigned short* cdB = cd + (size_t)batch * N_ * D_;
    const float* cNB = cN + batch * N_;
    const int c0w = cchunk * 512 + wv * 128;

    // ---- phase 1: branch-free survivor scan (8 iters, fully unrolled) -----
    unsigned mask = 0;
    #pragma unroll
    for (int cc = 0; cc < 8; ++cc) {
        int col = c0w + cc * 16 + (lane & 15);
        short8 bfrag = *reinterpret_cast<const short8*>(
            cdB + (size_t)col * D_ + (lane >> 4) * 8);
        float ny = cNB[col];
        f32x4 d[4];
        #pragma unroll
        for (int g = 0; g < 4; g++)
            d[g] = __builtin_amdgcn_mfma_f32_16x16x32_bf16(afrag[g], bfrag, cinit[g], 0, 0, 0);
        float m0 = fmaxf(fmaxf(d[0][0], d[0][1]), fmaxf(d[0][2], d[0][3]));
        float m1 = fmaxf(fmaxf(d[1][0], d[1][1]), fmaxf(d[1][2], d[1][3]));
        float m2 = fmaxf(fmaxf(d[2][0], d[2][1]), fmaxf(d[2][2], d[2][3]));
        float m3 = fmaxf(fmaxf(d[3][0], d[3][1]), fmaxf(d[3][2], d[3][3]));
        float mx = fmaxf(fmaxf(m0, m1), fmaxf(m2, m3));
        mask |= (__any(mx > ny - 10.0f) ? 1u : 0u) << cc;
    }

    // ---- phase 2: emit (rare) ---------------------------------------------
    auto push = [&](int T, int row, int colv, float em1) {
        size_t base = (size_t)(T * B_ + batch) * N_ + row;
        int idx = atomicAdd(&csr_cnt[base], 1);
        if (idx < RCAP)
            csr_ent[base * RCAP + idx] = make_uint2((unsigned)colv, __float_as_uint(em1));
    };
    while (mask) {
        int cc = __builtin_ctz(mask);
        mask &= mask - 1;
        int col = c0w + cc * 16 + (lane & 15);
        short8 bfrag = *reinterpret_cast<const short8*>(
            cdB + (size_t)col * D_ + (lane >> 4) * 8);
        float ny = cNB[col];
        f32x4 d[4];
        #pragma unroll
        for (int g = 0; g < 4; g++)
            d[g] = __builtin_amdgcn_mfma_f32_16x16x32_bf16(afrag[g], bfrag, cinit[g], 0, 0, 0);
        #pragma unroll
        for (int g = 0; g < 4; g++) {
            #pragma unroll
            for (int r = 0; r < 4; r++) {
                float dist = ny - d[g][r];
                if (dist < 10.0f) {
                    int i = r0 + g * 16 + (lane >> 4) * 4 + r;
                    if (m == 2) {
                        float em1 = __expf(__expf(-fmaxf(dist, 0.f))) - 1.0f;
                        push(2, i, col, em1);
                        push(3, col, i, em1);
                    } else if (i != col) {
                        float em1 = __expf(__expf(-fmaxf(dist, 0.f))) - 1.0f;
                        push(m, i, col, em1);
                    }
                }
            }
        }
    }
}

// ---------------------------------------------------------------------------
// Whole Sinkhorn loop, one 1024-thread block per batch.
// R9 diagnosis: the kernel is LDS-ISSUE-bound (~6cy/wave-DS-op): per-thread
// shfl reduces (18 ds_bpermute) + tree16 (48 reads) = ~1280 wave-DS/stage.
// R10 reduction plumbing, ~130 wave-DS/stage:
//   phase1: compute ev (regs) -> 3 evb writes + ONE float4 Sp[t] write
//   b1; wave 0 alone: 16 b128 reads + lane-reduce + one Sres write
//   b2; everyone: ONE broadcast Sres read -> gather (reg-cached CSR) -> log.
// Sp reuse WAR-safe (rewritten only after the barrier following all reads);
// evb parity double-buffered as before. 2 barriers/stage, 21 stages.
// ---------------------------------------------------------------------------
__global__ __launch_bounds__(1024) void sinkhorn_kernel(
    const float* __restrict__ a_in, const float* __restrict__ b_in,
    const int* __restrict__ csr_cnt, const uint2* __restrict__ csr_ent,
    float* __restrict__ out)
{
    __shared__ float evb[2][4][N_];     // 64 KB  [parity][slot][col]
    __shared__ float4 Sp[1024];         // 16 KB  per-thread partials
    __shared__ float4 Sres;
    __shared__ float resacc;

    const int batch = blockIdx.x;
    const int t = threadIdx.x, lane = t & 63, wv = t >> 6;

    int cnts[4][2];
    const uint2* ebase[4];
    uint2 ec[4][2][2];                  // cached entries [table][q][k]
    #pragma unroll
    for (int T = 0; T < 4; T++) {
        size_t bb = (size_t)(T * B_ + batch) * N_;
        ebase[T] = csr_ent + bb * (size_t)RCAP;
        #pragma unroll
        for (int q = 0; q < 2; q++) {
            int row = t + 1024 * q;
            int c = min(csr_cnt[bb + row], RCAP);
            cnts[T][q] = c;
            const uint2* E = ebase[T] + (size_t)row * RCAP;
            ec[T][q][0] = (c > 0) ? E[0] : make_uint2(0u, 0u);
            ec[T][q][1] = (c > 1) ? E[1] : make_uint2(0u, 0u);
        }
    }
    float AW[2], BW[2];
    float F0[2] = {0.f, 0.f}, F1[2] = {0.f, 0.f}, F2[2] = {0.f, 0.f}, F3[2] = {0.f, 0.f};
    #pragma unroll
    for (int q = 0; q < 2; q++) {
        int j = t + 1024 * q;
        AW[q] = (a_in[batch * N_ + j] - M_) * L2E;
        BW[q] = (b_in[batch * N_ + j] - M_) * L2E;
    }
    if (t == 0) resacc = 0.f;
    __syncthreads();

    // gather over this thread's CSR row: cached entries + rare global tail
    auto gath = [&](int T, int q, const float* evbuf) -> float {
        int c = cnts[T][q];
        float g = 0.f;
        if (c > 0) g += evbuf[ec[T][q][0].x] * __uint_as_float(ec[T][q][0].y);
        if (c > 1) g += evbuf[ec[T][q][1].x] * __uint_as_float(ec[T][q][1].y);
        if (__builtin_expect(c > 2, 0)) {
            const uint2* E = ebase[T] + (size_t)(t + 1024 * q) * RCAP;
            for (int k = 2; k < c; ++k)
                g += evbuf[E[k].x] * __uint_as_float(E[k].y);
        }
        return g;
    };

    // wave-0 reduction of Sp into Sres (components as needed)
    auto reduceS = [&](int ncomp) {
        if (wv == 0) {
            float4 v = Sp[lane];
            #pragma unroll
            for (int m = 1; m < 16; m++) {
                float4 u = Sp[lane + 64 * m];
                v.x += u.x; v.y += u.y; v.z += u.z; v.w += u.w;
            }
            #pragma unroll
            for (int off = 1; off < 64; off <<= 1) {
                v.x += __shfl_xor(v.x, off, 64);
                if (ncomp > 1) v.y += __shfl_xor(v.y, off, 64);
                if (ncomp > 2) v.z += __shfl_xor(v.z, off, 64);
                if (ncomp > 3) v.w += __shfl_xor(v.w, off, 64);
            }
            if (lane == 0) Sres = v;
        }
    };

    // stage A: fxx (T0, slot0, diag), fyx (T2, slot1), fyy (T1, slot2, diag)
    auto stageA = [&](int s) {
        const int p = s & 1;
        float e0q[2], e2q[2];
        float s0 = 0.f, s1 = 0.f, s2 = 0.f;
        #pragma unroll
        for (int q = 0; q < 2; q++) {
            int j = t + 1024 * q;
            float e0 = __builtin_amdgcn_exp2f(AW[q] + F0[q]); evb[p][0][j] = e0; e0q[q] = e0; s0 += e0;
            float e1 = __builtin_amdgcn_exp2f(AW[q] + F2[q]); evb[p][1][j] = e1;              s1 += e1;
            float e2 = __builtin_amdgcn_exp2f(BW[q] + F3[q]); evb[p][2][j] = e2; e2q[q] = e2; s2 += e2;
        }
        Sp[t] = make_float4(s0, s1, s2, 0.f);
        __syncthreads();                 // b1
        reduceS(3);
        __syncthreads();                 // b2
        float4 S = Sres;
        #pragma unroll
        for (int q = 0; q < 2; q++) {
            float g0 = gath(0, q, evb[p][0]);
            float g1 = gath(2, q, evb[p][1]);
            float g2 = gath(1, q, evb[p][2]);
            float lg0 = __builtin_amdgcn_logf(S.x + fmaf(e0q[q], EM1_DIAG, g0));
            float lg1 = __builtin_amdgcn_logf(S.y + g1);
            float lg2 = __builtin_amdgcn_logf(S.z + fmaf(e2q[q], EM1_DIAG, g2));
            F0[q] = fmaf(0.5f, F0[q], -fmaf(0.5f, lg0, MH_));
            F1[q] = fmaf(0.5f, F1[q], -fmaf(0.5f, lg1, MH_));
            F3[q] = fmaf(0.5f, F3[q], -fmaf(0.5f, lg2, MH_));
        }
    };

    // stage B: fxy (T3, cols y, c = b + fyx_new)
    auto stageB = [&](int s) {
        const int p = s & 1;
        float sB = 0.f;
        #pragma unroll
        for (int q = 0; q < 2; q++) {
            int j = t + 1024 * q;
            float e = __builtin_amdgcn_exp2f(BW[q] + F1[q]); evb[p][0][j] = e; sB += e;
        }
        Sp[t] = make_float4(sB, 0.f, 0.f, 0.f);
        __syncthreads();                 // b1
        reduceS(1);
        __syncthreads();                 // b2
        float S = Sres.x;
        #pragma unroll
        for (int q = 0; q < 2; q++) {
            float g = gath(3, q, evb[p][0]);
            F2[q] = fmaf(0.5f, F2[q], -fmaf(0.5f, __builtin_amdgcn_logf(S + g), MH_));
        }
    };

    int s = 0;
    for (int it = 0; it < 10; ++it) {
        stageA(s); ++s;
        stageB(s); ++s;
    }

    // stage E (s=20): 4 extrapolation LSEs + fused weighted reduce.
    // r = M + LN2*lg; in (r0-r2), (r3-r1) the M cancels.
    {
        const int p = s & 1;
        float e0q[2], e3q[2];
        float s0 = 0.f, s1 = 0.f, s2 = 0.f, s3 = 0.f;
        #pragma unroll
        for (int q = 0; q < 2; q++) {
            int j = t + 1024 * q;
            float e0 = __builtin_amdgcn_exp2f(AW[q] + F0[q]); evb[p][0][j] = e0; e0q[q] = e0; s0 += e0; // xx
            float e1 = __builtin_amdgcn_exp2f(AW[q] + F2[q]); evb[p][1][j] = e1;              s1 += e1; // yx
            float e2 = __builtin_amdgcn_exp2f(BW[q] + F1[q]); evb[p][2][j] = e2;              s2 += e2; // xy
            float e3 = __builtin_amdgcn_exp2f(BW[q] + F3[q]); evb[p][3][j] = e3; e3q[q] = e3; s3 += e3; // yy
        }
        Sp[t] = make_float4(s0, s1, s2, s3);
        __syncthreads();                 // b1
        reduceS(4);
        __syncthreads();                 // b2
        float4 S = Sres;
        float ctr = 0.f;
        #pragma unroll
        for (int q = 0; q < 2; q++) {
            float lg0 = __builtin_amdgcn_logf(S.x + fmaf(e0q[q], EM1_DIAG, gath(0, q, evb[p][0])));
            float lg1 = __builtin_amdgcn_logf(S.y + gath(2, q, evb[p][1]));
            float lg2 = __builtin_amdgcn_logf(S.z + gath(3, q, evb[p][2]));
            float lg3 = __builtin_amdgcn_logf(S.w + fmaf(e3q[q], EM1_DIAG, gath(1, q, evb[p][3])));
            float ea = __builtin_amdgcn_exp2f(AW[q]);   // e^{a-M}
            float eb = __builtin_amdgcn_exp2f(BW[q]);   // e^{b-M}
            ctr += (lg0 - lg2) * ea + (lg3 - lg1) * eb;
        }
        ctr *= (LN2 * EM_);
        #pragma unroll
        for (int off = 1; off < 64; off <<= 1) ctr += __shfl_xor(ctr, off, 64);
        if (lane == 0) atomicAdd(&resacc, ctr);
        __syncthreads();
        if (t == 0) out[batch] = resacc;   // EPSILON = 1
    }
}

// ---------------------------------------------------------------------------
extern "C" void kernel_launch(void* const* d_in, const int* in_sizes, int n_in,
                              void* d_out, int out_size, void* d_ws, size_t ws_size,
                              hipStream_t stream)
{
    const float* x = (const float*)d_in[0];
    const float* a = (const float*)d_in[1];
    const float* y = (const float*)d_in[2];
    const float* b = (const float*)d_in[3];
    float* out = (float*)d_out;

    char* ws = (char*)d_ws;
    size_t o = 0;
    unsigned short* xb = (unsigned short*)(ws + o); o += (size_t)B_ * N_ * D_ * 2;
    unsigned short* yb = (unsigned short*)(ws + o); o += (size_t)B_ * N_ * D_ * 2;
    float* NX = (float*)(ws + o); o += (size_t)B_ * N_ * 4;
    float* NY = (float*)(ws + o); o += (size_t)B_ * N_ * 4;
    int* csr_cnt = (int*)(ws + o); o += (size_t)4 * B_ * N_ * 4;            // 256 KB
    uint2* csr_ent = (uint2*)(ws + o); o += (size_t)4 * B_ * N_ * RCAP * 8; // 8 MB

    setup_kernel<<<128, 256, 0, stream>>>(x, y, xb, yb, NX, NY, csr_cnt);
    discover_kernel<<<3 * 1024, 256, 0, stream>>>(xb, yb, NX, NY, csr_cnt, csr_ent);
    sinkhorn_kernel<<<B_, 1024, 0, stream>>>(a, b, csr_cnt, csr_ent, out);
}